// Round 4
// baseline (268.211 us; speedup 1.0000x reference)
//
#include <hip/hip_runtime.h>

#define NN 2048   // factor dim
#define KK 16     // nonzeros per row

// ---------------------------------------------------------------------------
// Fused compose: mcl = scaling * (W0 @ W1 @ W2) in coefficient form,
// residue-major: mcl[((s*16 + j)*16) + i] for col c = s + 128*j, coefficient
// of x[((c-3) mod 128) + 128*i].
//
// Derivation (mechanical inline of the two verified kernels):
//   mcl_raw[c][i] = sum_k2 v2[r1*16+k2] * w01[r1][i],  r1 = (c-2-128*k2) mod N
//   w01[r1][i]    = sum_k1 v1[r0*16+k1] * v0[rx*16+k0]
//     with cm = (r1-1) mod N = (c-3-128*k2) mod N, s1 = cm&127, t1 = cm>>7,
//     rx = s1 + 128*i, r0 = (cm-128*k1) mod N, k0 = (t1-k1-i)&15.
// Key invariants: s1 = (c-3)&127 and rx are k2-INDEPENDENT (128*k2 == 0 mod
// 128), and t1 = (T0 - k2)&15 with T0 = ((c-3) mod N)>>7.  So the 16 v0
// values load once per thread.  k0 = (T0 - k2 - k1 - i)&15: pre-rotating the
// v0 row by the runtime amount (T0 - i) at LOAD time makes every register
// index compile-time ((k1+k2)&15) -> no scratch (rule #20).
// ---------------------------------------------------------------------------
__global__ __launch_bounds__(128) void sfd_compose(const float* __restrict__ v0,
                                                   const float* __restrict__ v1,
                                                   const float* __restrict__ v2,
                                                   const float* __restrict__ scaling,
                                                   float* __restrict__ mcl) {
  int tid = blockIdx.x * 128 + threadIdx.x;   // 32768 threads: (c, i)
  int c = tid >> 4;
  int i = tid & 15;

  int A  = (c + NN - 3) & (NN - 1);           // (c-3) mod N
  int s1 = A & 127;
  int T0 = A >> 7;
  int rx = s1 + (i << 7);

  // Pre-rotated v0 row: vr[m] = v0[rx*16 + ((T0 - i - m) & 15)]
  float vr[16];
#pragma unroll
  for (int m = 0; m < 16; ++m)
    vr[m] = v0[rx * 16 + ((T0 - i - m) & 15)];

  float acc = 0.f;
#pragma unroll 4
  for (int k2 = 0; k2 < 16; ++k2) {
    int r1 = (c + NN - 2 - (k2 << 7)) & (NN - 1);
    int cm = (r1 + NN - 1) & (NN - 1);
    float w = 0.f;
#pragma unroll
    for (int k1 = 0; k1 < 16; ++k1) {
      int r0 = (cm - (k1 << 7)) & (NN - 1);
      w = fmaf(v1[r0 * 16 + k1], vr[(k1 + k2) & 15], w);
    }
    acc = fmaf(v2[r1 * 16 + k2], w, acc);
  }
  int s = c & 127;
  int j = c >> 7;
  mcl[(s * 16 + j) * 16 + i] = acc * scaling[0];
}

// ---------------------------------------------------------------------------
// Apply-stage helpers (all indices compile-time-unrollable).
// ---------------------------------------------------------------------------
__device__ __forceinline__ void sfd_loadq(float4 (&pf)[4], const float* __restrict__ x,
                                          int rb, int w0, int t) {
#pragma unroll
  for (int q = 0; q < 4; ++q) {
    int idx = t + (q << 8);                 // 0..1023 = rr*128 + ig*32 + uu
    int uu = idx & 31;
    int ig = (idx >> 5) & 3;                // i-group (4 i's)
    int rr = idx >> 7;                      // 0..7
    const float* xrow = x + (size_t)(rb + rr) * NN;
    int cb = w0 + uu + (ig << 9);           // w0+uu+128*(4*ig)
    pf[q].x = xrow[cb & (NN - 1)];
    pf[q].y = xrow[(cb + 128) & (NN - 1)];
    pf[q].z = xrow[(cb + 256) & (NN - 1)];
    pf[q].w = xrow[(cb + 384) & (NN - 1)];
  }
}

__device__ __forceinline__ void sfd_writeq(const float4 (&pf)[4], float* xs, int t) {
#pragma unroll
  for (int q = 0; q < 4; ++q) {
    int idx = t + (q << 8);
    int uu = idx & 31;
    int ig = (idx >> 5) & 3;
    int rr = idx >> 7;
    *(float4*)(xs + (rr * 32 + uu) * 20 + (ig << 2)) = pf[q];
  }
}

__device__ __forceinline__ void sfd_compute(const float* xs, int u,
                                            const float (&mc0)[16], const float (&mc1)[16],
                                            float bi0, float bi1,
                                            int rb, int c0, int c1,
                                            float* __restrict__ out) {
#pragma unroll 1
  for (int r = 0; r < 8; ++r) {
    const float4* xr = (const float4*)(xs + (r * 32 + u) * 20);
    float xv[16];
    *(float4*)(xv + 0)  = xr[0];
    *(float4*)(xv + 4)  = xr[1];
    *(float4*)(xv + 8)  = xr[2];
    *(float4*)(xv + 12) = xr[3];
    float acc0 = bi0, acc1 = bi1;
#pragma unroll
    for (int i = 0; i < 16; ++i) {
      acc0 = fmaf(xv[i], mc0[i], acc0);
      acc1 = fmaf(xv[i], mc1[i], acc1);
    }
    size_t ob = (size_t)(rb + r) * NN;
    __builtin_nontemporal_store(fmaxf(acc0, 0.f), &out[ob + c0]);
    __builtin_nontemporal_store(fmaxf(acc1, 0.f), &out[ob + c1]);
  }
}

// ---------------------------------------------------------------------------
// Apply: out[b][c] = relu( sum_i mcl[c][i] * x[b][(c-3)%128 + 128*i] + bias[c] )
// Block: strip of 32 residues (512 cols) x 32 batch rows; grid (4, 512).
// Thread (u=t&31, jp=t>>5) -> 2 cols c = S0+u+128*(2jp+{0,1}); 2x16
// coefficients in registers (rotated by `shift` to absorb the mod-128 wrap).
// LDS layout xs[buf][r][u][i] stride 20 floats: ds_read_b128, conflict-free.
//
// Round-4: DOUBLE-BUFFERED LDS (2 x 20 KiB) -> ONE barrier per chunk (was 2).
// Steady state per chunk: compute(buf) -> writeq(next chunk -> buf^1; its
// vmcnt wait covers loads issued a full chunk ago) -> loadq(chunk+2) ->
// barrier.  Buffer hazards: each buffer is re-written only after the barrier
// that followed the completion of its last readers (verified per-barrier).
// Loads are now in flight across the whole chunk instead of draining at the
// second barrier.
//
// launch_bounds(256,4): 128-VGPR budget (Round-2 showed (256,8)'s 64-VGPR
// cap spills the prefetch regs).  LDS 40 KiB -> 4 blocks/CU.
// ---------------------------------------------------------------------------
__global__ __launch_bounds__(256, 4) void sfd_apply(const float* __restrict__ x,
                                                    const float* __restrict__ mcl,
                                                    const float* __restrict__ bias,
                                                    float* __restrict__ out) {
  const int S0 = blockIdx.x << 5;             // strip base residue: 0,32,64,96
  const int b0 = blockIdx.y << 5;             // 32 batch rows per block
  const int t = threadIdx.x;
  const int u = t & 31;
  const int jp = t >> 5;                      // 0..7
  const int s = S0 + u;                       // residue (= col mod 128), < 128
  const int j0 = jp << 1;
  const int w0 = (S0 + 125) & 127;            // (S0 - 3) mod 128
  const int shift = (w0 + u) >> 7;            // 1 iff this thread's window wraps

  // 2x16 coefficients into registers, rotated by `shift`:
  // LDS slot i holds x[(s-3)%128 + 128*((i+shift)&15)].
  float mc0[16], mc1[16];
  {
    const float* r0p = mcl + ((s * 16 + j0) << 4);
#pragma unroll
    for (int i = 0; i < 16; ++i) {
      int ic = (i + shift) & 15;
      mc0[i] = r0p[ic];
      mc1[i] = r0p[16 + ic];
    }
  }
  const int c0 = s + (j0 << 7);
  const int c1 = c0 + 128;
  const float bi0 = bias[c0];
  const float bi1 = bias[c1];

  __shared__ float xs[2][8 * 32 * 20];        // 2 x 20480 B double buffer

  float4 pfA[4], pfB[4];

  // Prologue: stage chunk0 into buf0, start chunk1 loads.
  sfd_loadq(pfA, x, b0 + 0,  w0, t);
  sfd_writeq(pfA, xs[0], t);
  sfd_loadq(pfB, x, b0 + 8,  w0, t);
  __syncthreads();                            // barrier 1: buf0 ready

  // Chunk 0 (read buf0); stage chunk1 -> buf1; issue chunk2 loads.
  sfd_compute(xs[0], u, mc0, mc1, bi0, bi1, b0 + 0,  c0, c1, out);
  sfd_writeq(pfB, xs[1], t);                  // vmcnt hidden by compute above
  sfd_loadq(pfA, x, b0 + 16, w0, t);
  __syncthreads();                            // barrier 2: buf1 ready, buf0 free

  // Chunk 1 (read buf1); stage chunk2 -> buf0; issue chunk3 loads.
  sfd_compute(xs[1], u, mc0, mc1, bi0, bi1, b0 + 8,  c0, c1, out);
  sfd_writeq(pfA, xs[0], t);
  sfd_loadq(pfB, x, b0 + 24, w0, t);
  __syncthreads();                            // barrier 3: buf0 ready, buf1 free

  // Chunk 2 (read buf0); stage chunk3 -> buf1.
  sfd_compute(xs[0], u, mc0, mc1, bi0, bi1, b0 + 16, c0, c1, out);
  sfd_writeq(pfB, xs[1], t);
  __syncthreads();                            // barrier 4: buf1 ready

  // Chunk 3 (read buf1).
  sfd_compute(xs[1], u, mc0, mc1, bi0, bi1, b0 + 24, c0, c1, out);
}

extern "C" void kernel_launch(void* const* d_in, const int* in_sizes, int n_in,
                              void* d_out, int out_size, void* d_ws, size_t ws_size,
                              hipStream_t stream) {
  // 0:x 1:vals0 2:vals1 3:vals2 4:rows0 5:cols0 6:rows1 7:cols1 8:rows2 9:cols2
  // 10:scaling 11:bias
  const float* x       = (const float*)d_in[0];
  const float* v0      = (const float*)d_in[1];
  const float* v1      = (const float*)d_in[2];
  const float* v2      = (const float*)d_in[3];
  const float* scaling = (const float*)d_in[10];
  const float* bias    = (const float*)d_in[11];
  float* out = (float*)d_out;

  float* mcl = (float*)d_ws;          // 2048*16 floats = 128 KiB

  const int B = in_sizes[0] / NN;     // 16384

  hipLaunchKernelGGL(sfd_compose, dim3(256), dim3(128), 0, stream, v0, v1, v2, scaling, mcl);
  hipLaunchKernelGGL(sfd_apply, dim3(4, B >> 5), dim3(256), 0, stream, x, mcl, bias, out);
}